// Round 14
// baseline (866.975 us; speedup 1.0000x reference)
//
#include <hip/hip_runtime.h>

#define T_TOK 2048
#define NE 16
#define KTOP 4
#define HD 2048
#define ID 1408
#define SID 5632
#define CAPACITY 1024

typedef __attribute__((ext_vector_type(8))) short short8;   // 8 x bf16
typedef __attribute__((ext_vector_type(4))) float floatx4;  // MFMA acc

__device__ __forceinline__ short f2b(float f){
  union { float f; unsigned u; } v; v.f = f;
  unsigned r = v.u + 0x7fffu + ((v.u >> 16) & 1u);
  return (short)(r >> 16);
}
__device__ __forceinline__ float b2f(short s){
  union { float f; unsigned u; } v; v.u = ((unsigned)(unsigned short)s) << 16;
  return v.f;
}
__device__ __forceinline__ unsigned cvt_pk(float a, float b){
  unsigned r;
  asm("v_cvt_pk_bf16_f32 %0, %1, %2" : "=v"(r) : "v"(a), "v"(b));
  return r;
}
__device__ __forceinline__ short8 cvt8(float4 a, float4 b){
  union { unsigned d[4]; short8 s; } u;
  u.d[0] = cvt_pk(a.x, a.y); u.d[1] = cvt_pk(a.z, a.w);
  u.d[2] = cvt_pk(b.x, b.y); u.d[3] = cvt_pk(b.z, b.w);
  return u.s;
}
__device__ __forceinline__ void gl16(const void* g, void* l){
  __builtin_amdgcn_global_load_lds(
      (const __attribute__((address_space(1))) void*)g,
      (__attribute__((address_space(3))) void*)l, 16, 0, 0);
}

// fp32->bf16 streaming convert, two streams (sizes in short8-groups).
__device__ __forceinline__ void conv_range(
    int cb, int ncb,
    const float* __restrict__ s1, short* __restrict__ d1, long long n1,
    const float* __restrict__ s2, short* __restrict__ d2, long long n2)
{
  const long long tot = n1 + n2;
  const long long stride = (long long)ncb * 256;
  #pragma unroll 2
  for (long long i = (long long)cb * 256 + threadIdx.x; i < tot; i += stride){
    const float* s; short8* d; long long j;
    if (i < n1){ s = s1; d = (short8*)d1; j = i; }
    else       { s = s2; d = (short8*)d2; j = i - n1; }
    float4 f0 = ((const float4*)s)[j * 2];
    float4 f1 = ((const float4*)s)[j * 2 + 1];
    d[j] = cvt8(f0, f1);
  }
}
__device__ __forceinline__ void conv3(
    int cb, int ncb,
    const float* __restrict__ s1, short* __restrict__ d1, long long n1,
    const float* __restrict__ s2, short* __restrict__ d2, long long n2,
    const float* __restrict__ s3, short* __restrict__ d3, long long n3)
{
  const long long tot = n1 + n2 + n3;
  const long long stride = (long long)ncb * 256;
  #pragma unroll 2
  for (long long i = (long long)cb * 256 + threadIdx.x; i < tot; i += stride){
    const float* s; short8* d; long long j;
    if (i < n1){ s = s1; d = (short8*)d1; j = i; }
    else if (i < n1 + n2){ s = s2; d = (short8*)d2; j = i - n1; }
    else { s = s3; d = (short8*)d3; j = i - n1 - n2; }
    float4 f0 = ((const float4*)s)[j * 2];
    float4 f1 = ((const float4*)s)[j * 2 + 1];
    d[j] = cvt8(f0, f1);
  }
}

// Router (blocks 0..511) + conv3(wsg,wsu,wsd) on blocks 512+ (R11 placement).
__global__ void moe_router(const float* __restrict__ x,
                           const float* __restrict__ gate_w,
                           const float* __restrict__ sg_w,
                           float* __restrict__ logits_out,
                           short* __restrict__ xb,
                           int* __restrict__ counts,
                           int* __restrict__ slot_token,
                           int* __restrict__ tslot,
                           float* __restrict__ tw,
                           float* __restrict__ sg,
                           const float* cs1, short* cd1, long long cn1,
                           const float* cs2, short* cd2, long long cn2,
                           const float* cs3, short* cd3, long long cn3)
{
  if (blockIdx.x >= 512){
    conv3(blockIdx.x - 512, gridDim.x - 512, cs1, cd1, cn1, cs2, cd2, cn2, cs3, cd3, cn3);
    return;
  }
  int wave = threadIdx.x >> 6, lane = threadIdx.x & 63;
  int t = (blockIdx.x << 2) + wave;
  const float4* xr = (const float4*)(x + (size_t)t * HD);
  short8* xbw = (short8*)(xb + (size_t)t * HD);
  float acc[17];
  #pragma unroll
  for (int e = 0; e < 17; ++e) acc[e] = 0.f;
  #pragma unroll
  for (int j = 0; j < 4; ++j){
    int i4 = (j * 64 + lane) * 2;
    float4 x0 = xr[i4], x1 = xr[i4 + 1];
    xbw[j * 64 + lane] = cvt8(x0, x1);
    #pragma unroll
    for (int e = 0; e < 16; ++e){
      const float4* gr = (const float4*)(gate_w + e * HD);
      float4 g0 = gr[i4], g1 = gr[i4 + 1];
      acc[e] += x0.x*g0.x + x0.y*g0.y + x0.z*g0.z + x0.w*g0.w
              + x1.x*g1.x + x1.y*g1.y + x1.z*g1.z + x1.w*g1.w;
    }
    const float4* sr = (const float4*)sg_w;
    float4 s0 = sr[i4], s1 = sr[i4 + 1];
    acc[16] += x0.x*s0.x + x0.y*s0.y + x0.z*s0.z + x0.w*s0.w
             + x1.x*s1.x + x1.y*s1.y + x1.z*s1.z + x1.w*s1.w;
  }
  #pragma unroll
  for (int e = 0; e < 17; ++e){
    float v = acc[e];
    #pragma unroll
    for (int off = 32; off > 0; off >>= 1) v += __shfl_xor(v, off, 64);
    acc[e] = v;
  }
  if (lane == 0){
    float m = acc[0];
    #pragma unroll
    for (int e = 1; e < 16; ++e) m = fmaxf(m, acc[e]);
    float p[16]; float s = 0.f;
    #pragma unroll
    for (int e = 0; e < 16; ++e){ p[e] = expf(acc[e] - m); s += p[e]; }
    float inv = 1.f / s;
    #pragma unroll
    for (int e = 0; e < 16; ++e) logits_out[t * 16 + e] = acc[e];
    unsigned used = 0;
    for (int k = 0; k < KTOP; ++k){
      float best = -1.f; int bi = 0;
      #pragma unroll
      for (int e = 0; e < 16; ++e){
        float pe = ((used >> e) & 1u) ? -1.f : p[e];
        if (pe > best){ best = pe; bi = e; }
      }
      used |= (1u << bi);
      int pos = atomicAdd(&counts[bi], 1);
      int enc = -1;
      if (pos < CAPACITY){
        slot_token[bi * CAPACITY + pos] = t;
        enc = bi * CAPACITY + pos;
      }
      tslot[t * KTOP + k] = enc;
      tw[t * KTOP + k] = best * inv;
    }
    sg[t] = 1.f / (1.f + expf(-acc[16]));
  }
}

// ---------------------------------------------------------------------------
// WIDE GEMM bodies: BM=128, BK=32, bf16 weights, gl16-only staging, 3 bufs
// x 24KB, depth-2 counted vmcnt (6 loads/step -> 12/6/0), XOR swizzle
// (nf*8-line frag offsets preserve the (line&7) invariant - same proof as
// the R11 NF=4 body; 0 conflicts measured R2-R13).
// gateup: BN=128 PER MATRIX (wave = 64m x 64n x 2 mats, acc 128 VGPR).
// down:   BN=256            (wave = 64m x 128n,        acc 128 VGPR).
// Halves LDS bytes/FLOP vs R11; doubles MFMA phase per in-flight load.
// ---------------------------------------------------------------------------

#define GEMM_PREAMBLE \
  const int tid = threadIdx.x; \
  const int lane = tid & 63, wave = tid >> 6; \
  const int wr = wave >> 1, wc = wave & 1; \
  const int lrow = lane & 15, lk = lane >> 4; \
  const int s_th = (tid & 7) ^ ((tid >> 3) & 7); \
  const int koff = (s_th & 3) << 3; \
  const int rloc = ((tid >> 3) << 1) + (s_th >> 2); \
  const int lb = lrow >> 1; \
  const int soff = (((((lrow & 1) << 2) | lk) ^ (lb & 7)) << 4); \
  const int abase = (wr * 32 + lb) * 128 + soff;

#define WAIT12 asm volatile("s_waitcnt vmcnt(12)" ::: "memory");
#define WAIT6  asm volatile("s_waitcnt vmcnt(6)" ::: "memory");
#define WAIT0  asm volatile("s_waitcnt vmcnt(0)" ::: "memory");
#define SBAR   asm volatile("s_barrier" ::: "memory");

// Fused gate+up GEMM: BN=128 per matrix. Buf 24K: A 8K | Bg 8K | Bu 8K.
__device__ __forceinline__ void dev_gateup(
    char (&smem)[3][24576],
    const short* __restrict__ Asrc,
    const short* __restrict__ Wg, const short* __restrict__ Wu,
    short* __restrict__ Out,
    const int* __restrict__ counts, const int* __restrict__ slot_token,
    int Ndim, int Kdim, int expert_mode, int mtiles, int ntiles,
    int bid, int nwg)
{
  int wg = ((bid & 7) * (nwg >> 3)) + (bid >> 3);  // XCD chunk (nwg%8==0)
  int m_t = wg % mtiles; wg /= mtiles;
  int n_t = wg % ntiles; int e = wg / ntiles;

  int cnt = T_TOK; size_t woff = 0; short* out = Out;
  if (expert_mode){
    cnt = counts[e]; if (cnt > CAPACITY) cnt = CAPACITY;
    if (m_t * 128 >= cnt) return;
    woff = (size_t)e * Ndim * Kdim;
    out = Out + (size_t)e * CAPACITY * Ndim;
  }
  const int m0 = m_t * 128, n0 = n_t * 128;

  GEMM_PREAMBLE
  const int browb = wc * 4096 + lb * 128 + soff;   // 64 rows = 32 lines per wc

  const short* aP0;
  const short* aP1;
  {
    int p0 = m0 + rloc, p1 = m0 + 64 + rloc;
    if (expert_mode){
      int q0 = (p0 < cnt) ? p0 : 0, q1 = (p1 < cnt) ? p1 : 0;
      aP0 = Asrc + (size_t)slot_token[e * CAPACITY + q0] * Kdim + koff;
      aP1 = Asrc + (size_t)slot_token[e * CAPACITY + q1] * Kdim + koff;
    } else {
      aP0 = Asrc + (size_t)p0 * Kdim + koff;
      aP1 = Asrc + (size_t)p1 * Kdim + koff;
    }
  }
  const short* bgP0 = Wg + woff + (size_t)(n0 + rloc) * Kdim + koff;
  const short* bgP1 = Wg + woff + (size_t)(n0 + 64 + rloc) * Kdim + koff;
  const short* buP0 = Wu + woff + (size_t)(n0 + rloc) * Kdim + koff;
  const short* buP1 = Wu + woff + (size_t)(n0 + 64 + rloc) * Kdim + koff;

  const floatx4 vzero = {0.f, 0.f, 0.f, 0.f};
  floatx4 accg[4][4], accu[4][4];
  #pragma unroll
  for (int i = 0; i < 4; ++i)
    #pragma unroll
    for (int j = 0; j < 4; ++j){ accg[i][j] = vzero; accu[i][j] = vzero; }

#define GU_ISSUE(B, T) { char* _b = (B); const int _k = (T) << 5; \
    gl16(aP0 + _k, _b + tid * 16); \
    gl16(aP1 + _k, _b + 4096 + tid * 16); \
    gl16(bgP0 + _k, _b + 8192 + tid * 16); \
    gl16(bgP1 + _k, _b + 12288 + tid * 16); \
    gl16(buP0 + _k, _b + 16384 + tid * 16); \
    gl16(buP1 + _k, _b + 20480 + tid * 16); }

#define GU_COMPUTE(B) { const char* bb = (B); \
    short8 a[4], bg[4], bu[4]; \
    _Pragma("unroll") \
    for (int mf = 0; mf < 4; ++mf) a[mf] = *(const short8*)(bb + abase + mf * 1024); \
    _Pragma("unroll") \
    for (int nf = 0; nf < 4; ++nf) bg[nf] = *(const short8*)(bb + 8192 + browb + nf * 1024); \
    __builtin_amdgcn_s_setprio(1); \
    _Pragma("unroll") \
    for (int mf = 0; mf < 4; ++mf) \
      _Pragma("unroll") \
      for (int nf = 0; nf < 4; ++nf) \
        accg[mf][nf] = __builtin_amdgcn_mfma_f32_16x16x32_bf16(a[mf], bg[nf], accg[mf][nf], 0, 0, 0); \
    __builtin_amdgcn_s_setprio(0); \
    _Pragma("unroll") \
    for (int nf = 0; nf < 4; ++nf) bu[nf] = *(const short8*)(bb + 16384 + browb + nf * 1024); \
    __builtin_amdgcn_s_setprio(1); \
    _Pragma("unroll") \
    for (int mf = 0; mf < 4; ++mf) \
      _Pragma("unroll") \
      for (int nf = 0; nf < 4; ++nf) \
        accu[mf][nf] = __builtin_amdgcn_mfma_f32_16x16x32_bf16(a[mf], bu[nf], accu[mf][nf], 0, 0, 0); \
    __builtin_amdgcn_s_setprio(0); }

  const int NSTEP = Kdim >> 5;
  char* b0 = smem[0];
  char* b1 = smem[1];
  char* b2 = smem[2];
  GU_ISSUE(b0, 0)
  GU_ISSUE(b1, 1)
  for (int s = 0; s < NSTEP; ++s){
    if (s + 2 < NSTEP){ GU_ISSUE(b2, s + 2) WAIT12 }
    else if (s + 2 == NSTEP){ WAIT6 }
    else { WAIT0 }
    SBAR
    GU_COMPUTE(b0)
    SBAR
    char* t = b0; b0 = b1; b1 = b2; b2 = t;
  }

  // epilogue: SiLU(g)*u -> bf16. C/D: col = lane&15, row = 4*(lane>>4)+r
  const int colbase = n0 + wc * 64 + lrow;
  #pragma unroll
  for (int mf = 0; mf < 4; ++mf){
    int pr = m0 + wr * 64 + mf * 16 + lk * 4;
    #pragma unroll
    for (int nf = 0; nf < 4; ++nf){
      floatx4 g4 = accg[mf][nf], u4 = accu[mf][nf];
      int col = colbase + nf * 16;
      #pragma unroll
      for (int r = 0; r < 4; ++r){
        float gv = g4[r], uv = u4[r];
        float a = (gv / (1.f + __expf(-gv))) * uv;
        out[(size_t)(pr + r) * Ndim + col] = f2b(a);
      }
    }
  }
}

// Down GEMM, BN=256. Buf 24K: A 8K | B 16K. expert -> eo; shared y = sig*C.
__device__ __forceinline__ void dev_down(
    char (&smem)[3][24576],
    const short* __restrict__ Asrc, const short* __restrict__ Wd,
    float* __restrict__ y, short* __restrict__ eo,
    const int* __restrict__ counts, const int* __restrict__ slot_token,
    const float* __restrict__ sgate,
    int Kdim, int expert_mode, int mtiles, int ntiles, int bid, int nwg)
{
  int wg = ((bid & 7) * (nwg >> 3)) + (bid >> 3);
  int m_t = wg % mtiles; wg /= mtiles;
  int n_t = wg % ntiles; int e = wg / ntiles;

  int cnt = T_TOK; const short* ab = Asrc; size_t woff = 0;
  if (expert_mode){
    cnt = counts[e]; if (cnt > CAPACITY) cnt = CAPACITY;
    if (m_t * 128 >= cnt) return;
    ab = Asrc + (size_t)e * CAPACITY * Kdim;
    woff = (size_t)e * HD * Kdim;
  }
  const int m0 = m_t * 128, n0 = n_t * 256;

  GEMM_PREAMBLE
  const int bbase = wc * 8192 + lb * 128 + soff;   // 128 rows = 64 lines per wc

  const short* aP0 = ab + (size_t)(m0 + rloc) * Kdim + koff;
  const short* aP1 = ab + (size_t)(m0 + 64 + rloc) * Kdim + koff;
  const short* bP0 = Wd + woff + (size_t)(n0 + rloc) * Kdim + koff;
  const short* bP1 = Wd + woff + (size_t)(n0 + 64 + rloc) * Kdim + koff;
  const short* bP2 = Wd + woff + (size_t)(n0 + 128 + rloc) * Kdim + koff;
  const short* bP3 = Wd + woff + (size_t)(n0 + 192 + rloc) * Kdim + koff;

  const floatx4 vzero = {0.f, 0.f, 0.f, 0.f};
  floatx4 acc[4][8];
  #pragma unroll
  for (int i = 0; i < 4; ++i)
    #pragma unroll
    for (int j = 0; j < 8; ++j) acc[i][j] = vzero;

#define DN_ISSUE(B, T) { char* _b = (B); const int _k = (T) << 5; \
    gl16(aP0 + _k, _b + tid * 16); \
    gl16(aP1 + _k, _b + 4096 + tid * 16); \
    gl16(bP0 + _k, _b + 8192 + tid * 16); \
    gl16(bP1 + _k, _b + 12288 + tid * 16); \
    gl16(bP2 + _k, _b + 16384 + tid * 16); \
    gl16(bP3 + _k, _b + 20480 + tid * 16); }

#define DN_COMPUTE(B) { const char* bb = (B); \
    short8 a[4], b[8]; \
    _Pragma("unroll") \
    for (int mf = 0; mf < 4; ++mf) a[mf] = *(const short8*)(bb + abase + mf * 1024); \
    _Pragma("unroll") \
    for (int nf = 0; nf < 4; ++nf) b[nf] = *(const short8*)(bb + 8192 + bbase + nf * 1024); \
    __builtin_amdgcn_s_setprio(1); \
    _Pragma("unroll") \
    for (int mf = 0; mf < 4; ++mf) \
      _Pragma("unroll") \
      for (int nf = 0; nf < 4; ++nf) \
        acc[mf][nf] = __builtin_amdgcn_mfma_f32_16x16x32_bf16(a[mf], b[nf], acc[mf][nf], 0, 0, 0); \
    __builtin_amdgcn_s_setprio(0); \
    _Pragma("unroll") \
    for (int nf = 4; nf < 8; ++nf) b[nf] = *(const short8*)(bb + 8192 + bbase + nf * 1024); \
    __builtin_amdgcn_s_setprio(1); \
    _Pragma("unroll") \
    for (int mf = 0; mf < 4; ++mf) \
      _Pragma("unroll") \
      for (int nf = 4; nf < 8; ++nf) \
        acc[mf][nf] = __builtin_amdgcn_mfma_f32_16x16x32_bf16(a[mf], b[nf], acc[mf][nf], 0, 0, 0); \
    __builtin_amdgcn_s_setprio(0); }

  const int NSTEP = Kdim >> 5;
  char* b0 = smem[0];
  char* b1 = smem[1];
  char* b2 = smem[2];
  DN_ISSUE(b0, 0)
  DN_ISSUE(b1, 1)
  for (int s = 0; s < NSTEP; ++s){
    if (s + 2 < NSTEP){ DN_ISSUE(b2, s + 2) WAIT12 }
    else if (s + 2 == NSTEP){ WAIT6 }
    else { WAIT0 }
    SBAR
    DN_COMPUTE(b0)
    SBAR
    char* t = b0; b0 = b1; b1 = b2; b2 = t;
  }

  const int colb = n0 + wc * 128 + lrow;
  if (expert_mode){
    #pragma unroll
    for (int mf = 0; mf < 4; ++mf){
      int pr = m0 + wr * 64 + mf * 16 + lk * 4;
      #pragma unroll
      for (int r = 0; r < 4; ++r){
        int p = pr + r;
        #pragma unroll
        for (int nf = 0; nf < 8; ++nf)
          eo[(size_t)(e * CAPACITY + p) * HD + colb + nf * 16] = f2b(acc[mf][nf][r]);
      }
    }
  } else {
    #pragma unroll
    for (int mf = 0; mf < 4; ++mf){
      int pr = m0 + wr * 64 + mf * 16 + lk * 4;
      #pragma unroll
      for (int r = 0; r < 4; ++r){
        int t = pr + r;
        float sv = sgate[t];
        #pragma unroll
        for (int nf = 0; nf < 8; ++nf)
          y[(size_t)t * HD + colb + nf * 16] = sv * acc[mf][nf][r];
      }
    }
  }
}

// D2: conv(eg,eu) [0,512) + shared gate/up (16mt x 44nt, K=2048).
__global__ __launch_bounds__(256) void moe_gateup_sh(
    const short* __restrict__ xb,
    const short* __restrict__ wbsg, const short* __restrict__ wbsu,
    short* __restrict__ acts,
    const float* cs1, short* cd1, long long cn1,
    const float* cs2, short* cd2, long long cn2, int conv_nwg)
{
  __shared__ __align__(16) char smem[3][24576];
  if ((int)blockIdx.x < conv_nwg){
    conv_range(blockIdx.x, conv_nwg, cs1, cd1, cn1, cs2, cd2, cn2);
    return;
  }
  dev_gateup(smem, xb, wbsg, wbsu, acts, nullptr, nullptr, SID, HD, 0, 16, 44,
             blockIdx.x - conv_nwg, gridDim.x - conv_nwg);
}

// D3: conv(ed) [0,512) | shared-down BN=256 [512,640) | expert gate/up [640,2048).
__global__ __launch_bounds__(256) void moe_mid(
    const short* __restrict__ xb,
    const short* __restrict__ wbeg, const short* __restrict__ wbeu,
    short* __restrict__ act,
    const short* __restrict__ acts, const short* __restrict__ wbsd,
    float* __restrict__ y, const float* __restrict__ sg,
    const int* __restrict__ counts, const int* __restrict__ slot_token,
    const float* ed, short* wbed, long long n_ed)
{
  __shared__ __align__(16) char smem[3][24576];
  int bx = blockIdx.x;
  if (bx < 512){
    conv_range(bx, 512, ed, wbed, n_ed, nullptr, nullptr, 0);
    return;
  }
  bx -= 512;
  if (bx < 128){
    dev_down(smem, acts, wbsd, y, nullptr, nullptr, nullptr, sg,
             SID, 0, 16, 8, bx, 128);
    return;
  }
  bx -= 128;
  dev_gateup(smem, xb, wbeg, wbeu, act, counts, slot_token, ID, HD, 1, 8, 11,
             bx, 1408);
}

// D4: expert down (8mt x 8nt x 16e, BN=256) -> eo
__global__ __launch_bounds__(256) void moe_down_ex(
    const short* __restrict__ act, const short* __restrict__ wbed,
    float* __restrict__ y, short* __restrict__ eo,
    const int* __restrict__ counts, const int* __restrict__ slot_token)
{
  __shared__ __align__(16) char smem[3][24576];
  dev_down(smem, act, wbed, y, eo, counts, slot_token, nullptr,
           ID, 1, 8, 8, blockIdx.x, gridDim.x);
}

// D5: gather-combine  y[t] += sum_k w_k * eo[slot_k]
__global__ void moe_combine(const short* __restrict__ eo,
                            const int* __restrict__ tslot,
                            const float* __restrict__ tw,
                            float* __restrict__ y)
{
  int t = blockIdx.x;
  int o = threadIdx.x << 3;
  float* yp = y + (size_t)t * HD + o;
  float4 a0 = *(const float4*)yp, a1 = *(const float4*)(yp + 4);
  float acc[8] = {a0.x, a0.y, a0.z, a0.w, a1.x, a1.y, a1.z, a1.w};
  #pragma unroll
  for (int k = 0; k < KTOP; ++k){
    int s = tslot[t * KTOP + k];
    if (s >= 0){
      float w = tw[t * KTOP + k];
      short8 v = *(const short8*)(eo + (size_t)s * HD + o);
      #pragma unroll
      for (int j = 0; j < 8; ++j) acc[j] += w * b2f(v[j]);
    }
  }
  float4 r0 = {acc[0], acc[1], acc[2], acc[3]};
  float4 r1 = {acc[4], acc[5], acc[6], acc[7]};
  *(float4*)yp = r0; *(float4*)(yp + 4) = r1;
}

extern "C" void kernel_launch(void* const* d_in, const int* in_sizes, int n_in,
                              void* d_out, int out_size, void* d_ws, size_t ws_size,
                              hipStream_t stream)
{
  (void)in_sizes; (void)n_in; (void)out_size; (void)ws_size;
  const float* x       = (const float*)d_in[0];
  const float* gate_w  = (const float*)d_in[1];
  const float* we_gate = (const float*)d_in[2];
  const float* we_up   = (const float*)d_in[3];
  const float* we_down = (const float*)d_in[4];
  const float* wsg     = (const float*)d_in[5];
  const float* wsu     = (const float*)d_in[6];
  const float* wsd     = (const float*)d_in[7];
  const float* sg_w    = (const float*)d_in[8];

  float* y      = (float*)d_out;                 // [T, H]
  float* logits = y + (size_t)T_TOK * HD;        // [T, E]

  const size_t N_EW = (size_t)NE * ID * HD;      // 46,137,344 elems
  const size_t N_SW = (size_t)SID * HD;          // 11,534,336 elems
  const long long G_EW = (long long)(N_EW / 8);  // short8 groups
  const long long G_SW = (long long)(N_SW / 8);

  char* ws = (char*)d_ws;
  size_t off = 0;
  short* xb   = (short*)(ws + off); off += (size_t)T_TOK * HD * 2;
  short* wb   = (short*)(ws + off); off += (3 * N_EW + 3 * N_SW) * 2;  // 346 MB
  short* act  = (short*)(ws + off); off += (size_t)NE * CAPACITY * ID * 2;
  short* acts = (short*)(ws + off); off += (size_t)T_TOK * SID * 2;
  int*   slot_token = (int*)  (ws + off); off += 65536;
  int*   tslot      = (int*)  (ws + off); off += 32768;
  float* tw         = (float*)(ws + off); off += 32768;
  int*   counts     = (int*)  (ws + off); off += 256;
  float* sg         = (float*)(ws + off);

  short* wbeg = wb;
  short* wbeu = wb + N_EW;
  short* wbed = wb + 2 * N_EW;
  short* wbsg = wb + 3 * N_EW;
  short* wbsu = wb + 3 * N_EW + N_SW;
  short* wbsd = wb + 3 * N_EW + 2 * N_SW;
  // eo aliases wbeg (67.1 MB <= 92.3 MB): expert gate weights dead after
  // moe_mid's expert-gateup; moe_down_ex (writer of eo) runs strictly after.
  short* eo = wbeg;

  hipMemsetAsync(counts, 0, 64, stream);
  // D1: router + conv(wsg,wsu,wsd)
  moe_router<<<512 + 1024, 256, 0, stream>>>(x, gate_w, sg_w, logits, xb,
                                             counts, slot_token, tslot, tw, sg,
                                             wsg, wbsg, G_SW, wsu, wbsu, G_SW,
                                             wsd, wbsd, G_SW);
  // D2: conv(eg,eu) + shared gate/up (16mt x 44nt, BN=128/mat, K=2048)
  moe_gateup_sh<<<512 + 16 * 44, 256, 0, stream>>>(xb, wbsg, wbsu, acts,
                                                   we_gate, wbeg, G_EW,
                                                   we_up, wbeu, G_EW, 512);
  // D3: conv(ed) + shared-down(16x8, BN=256, K=5632) + expert gate/up (8x11x16)
  moe_mid<<<512 + 128 + 8 * 11 * NE, 256, 0, stream>>>(xb, wbeg, wbeu, act,
                                                       acts, wbsd, y, sg,
                                                       counts, slot_token,
                                                       we_down, wbed, G_EW);
  // D4: expert down (8mt x 8nt x 16e, BN=256, K=1408) -> eo
  moe_down_ex<<<8 * 8 * NE, 256, 0, stream>>>(act, wbed, y, eo, counts, slot_token);
  // D5: combine
  moe_combine<<<T_TOK, 256, 0, stream>>>(eo, tslot, tw, y);
}

// Round 15
// 734.440 us; speedup vs baseline: 1.1805x; 1.1805x over previous
//
#include <hip/hip_runtime.h>

#define T_TOK 2048
#define NE 16
#define KTOP 4
#define HD 2048
#define ID 1408
#define SID 5632
#define CAPACITY 1024

typedef __attribute__((ext_vector_type(8))) short short8;   // 8 x bf16
typedef __attribute__((ext_vector_type(4))) float floatx4;  // MFMA acc

// fp32 -> bf16 round-to-nearest-even (scalar)
__device__ __forceinline__ short f2b(float f){
  union { float f; unsigned u; } v; v.f = f;
  unsigned r = v.u + 0x7fffu + ((v.u >> 16) & 1u);
  return (short)(r >> 16);
}
__device__ __forceinline__ float b2f(short s){
  union { float f; unsigned u; } v; v.u = ((unsigned)(unsigned short)s) << 16;
  return v.f;
}
// hardware packed fp32->bf16 RNE
__device__ __forceinline__ unsigned cvt_pk(float a, float b){
  unsigned r;
  asm("v_cvt_pk_bf16_f32 %0, %1, %2" : "=v"(r) : "v"(a), "v"(b));
  return r;
}
__device__ __forceinline__ short8 cvt8(float4 a, float4 b){
  union { unsigned d[4]; short8 s; } u;
  u.d[0] = cvt_pk(a.x, a.y); u.d[1] = cvt_pk(a.z, a.w);
  u.d[2] = cvt_pk(b.x, b.y); u.d[3] = cvt_pk(b.z, b.w);
  return u.s;
}
// async global->LDS, 16B per lane
__device__ __forceinline__ void gl16(const void* g, void* l){
  __builtin_amdgcn_global_load_lds(
      (const __attribute__((address_space(1))) void*)g,
      (__attribute__((address_space(3))) void*)l, 16, 0, 0);
}

// fp32->bf16 streaming convert, two streams (sizes in short8-groups).
__device__ __forceinline__ void conv_range(
    int cb, int ncb,
    const float* __restrict__ s1, short* __restrict__ d1, long long n1,
    const float* __restrict__ s2, short* __restrict__ d2, long long n2)
{
  const long long tot = n1 + n2;
  const long long stride = (long long)ncb * 256;
  #pragma unroll 2
  for (long long i = (long long)cb * 256 + threadIdx.x; i < tot; i += stride){
    const float* s; short8* d; long long j;
    if (i < n1){ s = s1; d = (short8*)d1; j = i; }
    else       { s = s2; d = (short8*)d2; j = i - n1; }
    float4 f0 = ((const float4*)s)[j * 2];
    float4 f1 = ((const float4*)s)[j * 2 + 1];
    d[j] = cvt8(f0, f1);
  }
}
// three-stream variant
__device__ __forceinline__ void conv3(
    int cb, int ncb,
    const float* __restrict__ s1, short* __restrict__ d1, long long n1,
    const float* __restrict__ s2, short* __restrict__ d2, long long n2,
    const float* __restrict__ s3, short* __restrict__ d3, long long n3)
{
  const long long tot = n1 + n2 + n3;
  const long long stride = (long long)ncb * 256;
  #pragma unroll 2
  for (long long i = (long long)cb * 256 + threadIdx.x; i < tot; i += stride){
    const float* s; short8* d; long long j;
    if (i < n1){ s = s1; d = (short8*)d1; j = i; }
    else if (i < n1 + n2){ s = s2; d = (short8*)d2; j = i - n1; }
    else { s = s3; d = (short8*)d3; j = i - n1 - n2; }
    float4 f0 = ((const float4*)s)[j * 2];
    float4 f1 = ((const float4*)s)[j * 2 + 1];
    d[j] = cvt8(f0, f1);
  }
}

// Router (blocks 0..511) + conv3(wsg,wsu,wsd) on blocks 512+.
__global__ void moe_router(const float* __restrict__ x,
                           const float* __restrict__ gate_w,
                           const float* __restrict__ sg_w,
                           float* __restrict__ logits_out,
                           short* __restrict__ xb,
                           int* __restrict__ counts,
                           int* __restrict__ slot_token,
                           int* __restrict__ tslot,
                           float* __restrict__ tw,
                           float* __restrict__ sg,
                           const float* cs1, short* cd1, long long cn1,
                           const float* cs2, short* cd2, long long cn2,
                           const float* cs3, short* cd3, long long cn3)
{
  if (blockIdx.x >= 512){
    conv3(blockIdx.x - 512, gridDim.x - 512, cs1, cd1, cn1, cs2, cd2, cn2, cs3, cd3, cn3);
    return;
  }
  int wave = threadIdx.x >> 6, lane = threadIdx.x & 63;
  int t = (blockIdx.x << 2) + wave;
  const float4* xr = (const float4*)(x + (size_t)t * HD);
  short8* xbw = (short8*)(xb + (size_t)t * HD);
  float acc[17];
  #pragma unroll
  for (int e = 0; e < 17; ++e) acc[e] = 0.f;
  #pragma unroll
  for (int j = 0; j < 4; ++j){
    int i4 = (j * 64 + lane) * 2;
    float4 x0 = xr[i4], x1 = xr[i4 + 1];
    xbw[j * 64 + lane] = cvt8(x0, x1);
    #pragma unroll
    for (int e = 0; e < 16; ++e){
      const float4* gr = (const float4*)(gate_w + e * HD);
      float4 g0 = gr[i4], g1 = gr[i4 + 1];
      acc[e] += x0.x*g0.x + x0.y*g0.y + x0.z*g0.z + x0.w*g0.w
              + x1.x*g1.x + x1.y*g1.y + x1.z*g1.z + x1.w*g1.w;
    }
    const float4* sr = (const float4*)sg_w;
    float4 s0 = sr[i4], s1 = sr[i4 + 1];
    acc[16] += x0.x*s0.x + x0.y*s0.y + x0.z*s0.z + x0.w*s0.w
             + x1.x*s1.x + x1.y*s1.y + x1.z*s1.z + x1.w*s1.w;
  }
  #pragma unroll
  for (int e = 0; e < 17; ++e){
    float v = acc[e];
    #pragma unroll
    for (int off = 32; off > 0; off >>= 1) v += __shfl_xor(v, off, 64);
    acc[e] = v;
  }
  if (lane == 0){
    float m = acc[0];
    #pragma unroll
    for (int e = 1; e < 16; ++e) m = fmaxf(m, acc[e]);
    float p[16]; float s = 0.f;
    #pragma unroll
    for (int e = 0; e < 16; ++e){ p[e] = expf(acc[e] - m); s += p[e]; }
    float inv = 1.f / s;
    #pragma unroll
    for (int e = 0; e < 16; ++e) logits_out[t * 16 + e] = acc[e];
    unsigned used = 0;
    for (int k = 0; k < KTOP; ++k){
      float best = -1.f; int bi = 0;
      #pragma unroll
      for (int e = 0; e < 16; ++e){
        float pe = ((used >> e) & 1u) ? -1.f : p[e];
        if (pe > best){ best = pe; bi = e; }
      }
      used |= (1u << bi);
      int pos = atomicAdd(&counts[bi], 1);
      int enc = -1;
      if (pos < CAPACITY){
        slot_token[bi * CAPACITY + pos] = t;
        enc = bi * CAPACITY + pos;
      }
      tslot[t * KTOP + k] = enc;
      tw[t * KTOP + k] = best * inv;
    }
    sg[t] = 1.f / (1.f + expf(-acc[16]));
  }
}

// ---------------------------------------------------------------------------
// GEMM bodies (R11-verified optimum): BM=128, BK=32, bf16 weights,
// global_load_lds-only staging, 3 LDS bufs x 16KB (3 blocks/CU), depth-2
// counted vmcnt, raw s_barrier, XOR-involution swizzle (0 bank conflicts
// measured R2-R14). Measured falsifications pinning this configuration:
// depth-1 (R12) and 2-blocks/CU wide-tile (R14) both regress; setprio null
// (R10); fp32-direct (R4/R9) and reg-staging across barriers (R7) regress.
// ---------------------------------------------------------------------------

#define GEMM_PREAMBLE \
  const int tid = threadIdx.x; \
  const int lane = tid & 63, wave = tid >> 6; \
  const int wr = wave >> 1, wc = wave & 1; \
  const int lrow = lane & 15, lk = lane >> 4; \
  const int s_th = (tid & 7) ^ ((tid >> 3) & 7); \
  const int koff = (s_th & 3) << 3; \
  const int rloc = ((tid >> 3) << 1) + (s_th >> 2); \
  const int lb = lrow >> 1; \
  const int soff = (((((lrow & 1) << 2) | lk) ^ (lb & 7)) << 4); \
  const int abase = (wr * 32 + lb) * 128 + soff;

#define WAIT8  asm volatile("s_waitcnt vmcnt(8)" ::: "memory");
#define WAIT4  asm volatile("s_waitcnt vmcnt(4)" ::: "memory");
#define WAIT0  asm volatile("s_waitcnt vmcnt(0)" ::: "memory");
#define SBAR   asm volatile("s_barrier" ::: "memory");

// Fused gate+up GEMM: BN=64 per matrix, dual acc share the A tile.
__device__ __forceinline__ void dev_gateup(
    char (&smem)[3][16384],
    const short* __restrict__ Asrc,
    const short* __restrict__ Wg, const short* __restrict__ Wu,
    short* __restrict__ Out,
    const int* __restrict__ counts, const int* __restrict__ slot_token,
    int Ndim, int Kdim, int expert_mode, int mtiles, int ntiles,
    int bid, int nwg)
{
  int wg = ((bid & 7) * (nwg >> 3)) + (bid >> 3);  // XCD chunk (nwg%8==0)
  int m_t = wg % mtiles; wg /= mtiles;
  int n_t = wg % ntiles; int e = wg / ntiles;

  int cnt = T_TOK; size_t woff = 0; short* out = Out;
  if (expert_mode){
    cnt = counts[e]; if (cnt > CAPACITY) cnt = CAPACITY;
    if (m_t * 128 >= cnt) return;
    woff = (size_t)e * Ndim * Kdim;
    out = Out + (size_t)e * CAPACITY * Ndim;
  }
  const int m0 = m_t * 128, n0 = n_t * 64;

  GEMM_PREAMBLE
  const int gbase = 8192 + (wc * 16 + lb) * 128 + soff;

  const short* aP0;
  const short* aP1;
  {
    int p0 = m0 + rloc, p1 = m0 + 64 + rloc;
    if (expert_mode){
      int q0 = (p0 < cnt) ? p0 : 0, q1 = (p1 < cnt) ? p1 : 0;
      aP0 = Asrc + (size_t)slot_token[e * CAPACITY + q0] * Kdim + koff;
      aP1 = Asrc + (size_t)slot_token[e * CAPACITY + q1] * Kdim + koff;
    } else {
      aP0 = Asrc + (size_t)p0 * Kdim + koff;
      aP1 = Asrc + (size_t)p1 * Kdim + koff;
    }
  }
  const short* bgP = Wg + woff + (size_t)(n0 + rloc) * Kdim + koff;
  const short* buP = Wu + woff + (size_t)(n0 + rloc) * Kdim + koff;

  const floatx4 vzero = {0.f, 0.f, 0.f, 0.f};
  floatx4 accg[4][2], accu[4][2];
  #pragma unroll
  for (int i = 0; i < 4; ++i)
    #pragma unroll
    for (int j = 0; j < 2; ++j){ accg[i][j] = vzero; accu[i][j] = vzero; }

#define GU_ISSUE(B, T) { char* _b = (B); const int _k = (T) << 5; \
    gl16(aP0 + _k, _b + tid * 16); \
    gl16(aP1 + _k, _b + 4096 + tid * 16); \
    gl16(bgP + _k, _b + 8192 + tid * 16); \
    gl16(buP + _k, _b + 12288 + tid * 16); }

#define GU_COMPUTE(B) { const char* bb = (B); \
    short8 a[4], bg[2], bu[2]; \
    _Pragma("unroll") \
    for (int mf = 0; mf < 4; ++mf) a[mf] = *(const short8*)(bb + abase + mf * 1024); \
    _Pragma("unroll") \
    for (int nf = 0; nf < 2; ++nf){ \
      bg[nf] = *(const short8*)(bb + gbase + nf * 1024); \
      bu[nf] = *(const short8*)(bb + gbase + 4096 + nf * 1024); } \
    __builtin_amdgcn_s_setprio(1); \
    _Pragma("unroll") \
    for (int mf = 0; mf < 4; ++mf) \
      _Pragma("unroll") \
      for (int nf = 0; nf < 2; ++nf){ \
        accg[mf][nf] = __builtin_amdgcn_mfma_f32_16x16x32_bf16(a[mf], bg[nf], accg[mf][nf], 0, 0, 0); \
        accu[mf][nf] = __builtin_amdgcn_mfma_f32_16x16x32_bf16(a[mf], bu[nf], accu[mf][nf], 0, 0, 0); } \
    __builtin_amdgcn_s_setprio(0); }

  const int NSTEP = Kdim >> 5;
  char* b0 = smem[0];
  char* b1 = smem[1];
  char* b2 = smem[2];
  GU_ISSUE(b0, 0)
  GU_ISSUE(b1, 1)
  for (int s = 0; s < NSTEP; ++s){
    if (s + 2 < NSTEP){ GU_ISSUE(b2, s + 2) WAIT8 }
    else if (s + 2 == NSTEP){ WAIT4 }
    else { WAIT0 }
    SBAR
    GU_COMPUTE(b0)
    SBAR
    char* t = b0; b0 = b1; b1 = b2; b2 = t;
  }

  const int colbase = n0 + wc * 32 + lrow;
  #pragma unroll
  for (int mf = 0; mf < 4; ++mf){
    int pr = m0 + wr * 64 + mf * 16 + lk * 4;
    #pragma unroll
    for (int nf = 0; nf < 2; ++nf){
      floatx4 g4 = accg[mf][nf], u4 = accu[mf][nf];
      int col = colbase + nf * 16;
      #pragma unroll
      for (int r = 0; r < 4; ++r){
        float gv = g4[r], uv = u4[r];
        float a = (gv / (1.f + __expf(-gv))) * uv;
        out[(size_t)(pr + r) * Ndim + col] = f2b(a);
      }
    }
  }
}

// Down GEMM, BN=128 (NF=4). expert: -> eo; shared: y = sigmoid_gate * C.
__device__ __forceinline__ void dev_down4(
    char (&smem)[3][16384],
    const short* __restrict__ Asrc, const short* __restrict__ Wd,
    float* __restrict__ y, short* __restrict__ eo,
    const int* __restrict__ counts, const int* __restrict__ slot_token,
    const float* __restrict__ sgate,
    int Kdim, int expert_mode, int mtiles, int ntiles, int bid, int nwg)
{
  int wg = ((bid & 7) * (nwg >> 3)) + (bid >> 3);
  int m_t = wg % mtiles; wg /= mtiles;
  int n_t = wg % ntiles; int e = wg / ntiles;

  int cnt = T_TOK; const short* ab = Asrc; size_t woff = 0;
  if (expert_mode){
    cnt = counts[e]; if (cnt > CAPACITY) cnt = CAPACITY;
    if (m_t * 128 >= cnt) return;
    ab = Asrc + (size_t)e * CAPACITY * Kdim;
    woff = (size_t)e * HD * Kdim;
  }
  const int m0 = m_t * 128, n0 = n_t * 128;

  GEMM_PREAMBLE
  const int bbase = 8192 + (wc * 32 + lb) * 128 + soff;

  const short* aP0 = ab + (size_t)(m0 + rloc) * Kdim + koff;
  const short* aP1 = ab + (size_t)(m0 + 64 + rloc) * Kdim + koff;
  const short* bP0 = Wd + woff + (size_t)(n0 + rloc) * Kdim + koff;
  const short* bP1 = Wd + woff + (size_t)(n0 + 64 + rloc) * Kdim + koff;

  const floatx4 vzero = {0.f, 0.f, 0.f, 0.f};
  floatx4 acc[4][4];
  #pragma unroll
  for (int i = 0; i < 4; ++i)
    #pragma unroll
    for (int j = 0; j < 4; ++j) acc[i][j] = vzero;

#define DN_ISSUE(B, T) { char* _b = (B); const int _k = (T) << 5; \
    gl16(aP0 + _k, _b + tid * 16); \
    gl16(aP1 + _k, _b + 4096 + tid * 16); \
    gl16(bP0 + _k, _b + 8192 + tid * 16); \
    gl16(bP1 + _k, _b + 12288 + tid * 16); }

#define DN_COMPUTE(B) { const char* bb = (B); \
    short8 a[4], b[4]; \
    _Pragma("unroll") \
    for (int mf = 0; mf < 4; ++mf) a[mf] = *(const short8*)(bb + abase + mf * 1024); \
    _Pragma("unroll") \
    for (int nf = 0; nf < 4; ++nf) b[nf] = *(const short8*)(bb + bbase + nf * 1024); \
    __builtin_amdgcn_s_setprio(1); \
    _Pragma("unroll") \
    for (int mf = 0; mf < 4; ++mf) \
      _Pragma("unroll") \
      for (int nf = 0; nf < 4; ++nf) \
        acc[mf][nf] = __builtin_amdgcn_mfma_f32_16x16x32_bf16(a[mf], b[nf], acc[mf][nf], 0, 0, 0); \
    __builtin_amdgcn_s_setprio(0); }

  const int NSTEP = Kdim >> 5;
  char* b0 = smem[0];
  char* b1 = smem[1];
  char* b2 = smem[2];
  DN_ISSUE(b0, 0)
  DN_ISSUE(b1, 1)
  for (int s = 0; s < NSTEP; ++s){
    if (s + 2 < NSTEP){ DN_ISSUE(b2, s + 2) WAIT8 }
    else if (s + 2 == NSTEP){ WAIT4 }
    else { WAIT0 }
    SBAR
    DN_COMPUTE(b0)
    SBAR
    char* t = b0; b0 = b1; b1 = b2; b2 = t;
  }

  const int colb = n0 + wc * 64 + lrow;
  if (expert_mode){
    #pragma unroll
    for (int mf = 0; mf < 4; ++mf){
      int pr = m0 + wr * 64 + mf * 16 + lk * 4;
      #pragma unroll
      for (int r = 0; r < 4; ++r){
        int p = pr + r;
        #pragma unroll
        for (int nf = 0; nf < 4; ++nf)
          eo[(size_t)(e * CAPACITY + p) * HD + colb + nf * 16] = f2b(acc[mf][nf][r]);
      }
    }
  } else {
    #pragma unroll
    for (int mf = 0; mf < 4; ++mf){
      int pr = m0 + wr * 64 + mf * 16 + lk * 4;
      #pragma unroll
      for (int r = 0; r < 4; ++r){
        int t = pr + r;
        float sv = sgate[t];
        #pragma unroll
        for (int nf = 0; nf < 4; ++nf)
          y[(size_t)t * HD + colb + nf * 16] = sv * acc[mf][nf][r];
      }
    }
  }
}

// D2: shared gate/up GEMM + conv(eg,eu) on first conv_nwg blocks.
__global__ __launch_bounds__(256) void moe_gateup_sh(
    const short* __restrict__ xb,
    const short* __restrict__ wbsg, const short* __restrict__ wbsu,
    short* __restrict__ acts,
    const float* cs1, short* cd1, long long cn1,
    const float* cs2, short* cd2, long long cn2, int conv_nwg)
{
  __shared__ __align__(16) char smem[3][16384];
  if ((int)blockIdx.x < conv_nwg){
    conv_range(blockIdx.x, conv_nwg, cs1, cd1, cn1, cs2, cd2, cn2);
    return;
  }
  dev_gateup(smem, xb, wbsg, wbsu, acts, nullptr, nullptr, SID, HD, 0, 16, 88,
             blockIdx.x - conv_nwg, gridDim.x - conv_nwg);
}

// D3 fused: conv(ed) [0,512) | shared-down NF4 [512,768) | expert gate/up [768,3584).
__global__ __launch_bounds__(256) void moe_mid(
    const short* __restrict__ xb,
    const short* __restrict__ wbeg, const short* __restrict__ wbeu,
    short* __restrict__ act,
    const short* __restrict__ acts, const short* __restrict__ wbsd,
    float* __restrict__ y, const float* __restrict__ sg,
    const int* __restrict__ counts, const int* __restrict__ slot_token,
    const float* ed, short* wbed, long long n_ed)
{
  __shared__ __align__(16) char smem[3][16384];
  int bx = blockIdx.x;
  if (bx < 512){
    conv_range(bx, 512, ed, wbed, n_ed, nullptr, nullptr, 0);
    return;
  }
  bx -= 512;
  if (bx < 256){
    dev_down4(smem, acts, wbsd, y, nullptr, nullptr, nullptr, sg,
              SID, 0, 16, 16, bx, 256);
    return;
  }
  bx -= 256;
  dev_gateup(smem, xb, wbeg, wbeu, act, counts, slot_token, ID, HD, 1, 8, 22,
             bx, 2816);
}

// D4: expert down -> eo
__global__ __launch_bounds__(256) void moe_down_ex(
    const short* __restrict__ act, const short* __restrict__ wbed,
    float* __restrict__ y, short* __restrict__ eo,
    const int* __restrict__ counts, const int* __restrict__ slot_token)
{
  __shared__ __align__(16) char smem[3][16384];
  dev_down4(smem, act, wbed, y, eo, counts, slot_token, nullptr,
            ID, 1, 8, 16, blockIdx.x, gridDim.x);
}

// D5: gather-combine  y[t] += sum_k w_k * eo[slot_k]
__global__ void moe_combine(const short* __restrict__ eo,
                            const int* __restrict__ tslot,
                            const float* __restrict__ tw,
                            float* __restrict__ y)
{
  int t = blockIdx.x;
  int o = threadIdx.x << 3;
  float* yp = y + (size_t)t * HD + o;
  float4 a0 = *(const float4*)yp, a1 = *(const float4*)(yp + 4);
  float acc[8] = {a0.x, a0.y, a0.z, a0.w, a1.x, a1.y, a1.z, a1.w};
  #pragma unroll
  for (int k = 0; k < KTOP; ++k){
    int s = tslot[t * KTOP + k];
    if (s >= 0){
      float w = tw[t * KTOP + k];
      short8 v = *(const short8*)(eo + (size_t)s * HD + o);
      #pragma unroll
      for (int j = 0; j < 8; ++j) acc[j] += w * b2f(v[j]);
    }
  }
  float4 r0 = {acc[0], acc[1], acc[2], acc[3]};
  float4 r1 = {acc[4], acc[5], acc[6], acc[7]};
  *(float4*)yp = r0; *(float4*)(yp + 4) = r1;
}

extern "C" void kernel_launch(void* const* d_in, const int* in_sizes, int n_in,
                              void* d_out, int out_size, void* d_ws, size_t ws_size,
                              hipStream_t stream)
{
  (void)in_sizes; (void)n_in; (void)out_size; (void)ws_size;
  const float* x       = (const float*)d_in[0];
  const float* gate_w  = (const float*)d_in[1];
  const float* we_gate = (const float*)d_in[2];
  const float* we_up   = (const float*)d_in[3];
  const float* we_down = (const float*)d_in[4];
  const float* wsg     = (const float*)d_in[5];
  const float* wsu     = (const float*)d_in[6];
  const float* wsd     = (const float*)d_in[7];
  const float* sg_w    = (const float*)d_in[8];

  float* y      = (float*)d_out;                 // [T, H]
  float* logits = y + (size_t)T_TOK * HD;        // [T, E]

  const size_t N_EW = (size_t)NE * ID * HD;      // 46,137,344 elems
  const size_t N_SW = (size_t)SID * HD;          // 11,534,336 elems
  const long long G_EW = (long long)(N_EW / 8);  // short8 groups
  const long long G_SW = (long long)(N_SW / 8);

  char* ws = (char*)d_ws;
  size_t off = 0;
  short* xb   = (short*)(ws + off); off += (size_t)T_TOK * HD * 2;
  short* wb   = (short*)(ws + off); off += (3 * N_EW + 3 * N_SW) * 2;  // 346 MB
  short* act  = (short*)(ws + off); off += (size_t)NE * CAPACITY * ID * 2;
  short* acts = (short*)(ws + off); off += (size_t)T_TOK * SID * 2;
  int*   slot_token = (int*)  (ws + off); off += 65536;
  int*   tslot      = (int*)  (ws + off); off += 32768;
  float* tw         = (float*)(ws + off); off += 32768;
  int*   counts     = (int*)  (ws + off); off += 256;
  float* sg         = (float*)(ws + off);

  short* wbeg = wb;
  short* wbeu = wb + N_EW;
  short* wbed = wb + 2 * N_EW;
  short* wbsg = wb + 3 * N_EW;
  short* wbsu = wb + 3 * N_EW + N_SW;
  short* wbsd = wb + 3 * N_EW + 2 * N_SW;
  // eo aliases wbeg (67.1 MB <= 92.3 MB): expert gate weights dead after
  // moe_mid's expert-gateup; moe_down_ex (writer of eo) runs strictly after.
  short* eo = wbeg;

  hipMemsetAsync(counts, 0, 64, stream);
  // D1: router + conv(wsg,wsu,wsd)
  moe_router<<<512 + 1024, 256, 0, stream>>>(x, gate_w, sg_w, logits, xb,
                                             counts, slot_token, tslot, tw, sg,
                                             wsg, wbsg, G_SW, wsu, wbsu, G_SW,
                                             wsd, wbsd, G_SW);
  // D2: shared gate/up (16mt x 88nt, K=2048) + conv(eg,eu)
  moe_gateup_sh<<<512 + 16 * 88, 256, 0, stream>>>(xb, wbsg, wbsu, acts,
                                                   we_gate, wbeg, G_EW,
                                                   we_up, wbeu, G_EW, 512);
  // D3: conv(ed) + shared-down(16x16, BN=128, K=5632) + expert gate/up (8x22x16)
  moe_mid<<<512 + 256 + 2816, 256, 0, stream>>>(xb, wbeg, wbeu, act,
                                                acts, wbsd, y, sg,
                                                counts, slot_token,
                                                we_down, wbed, G_EW);
  // D4: expert down (8mt x 16nt x 16e, BN=128, K=1408) -> eo
  moe_down_ex<<<8 * 16 * NE, 256, 0, stream>>>(act, wbed, y, eo, counts, slot_token);
  // D5: combine
  moe_combine<<<T_TOK, 256, 0, stream>>>(eo, tslot, tw, y);
}